// Round 1
// baseline (1212.291 us; speedup 1.0000x reference)
//
#include <hip/hip_runtime.h>
#include <cstdint>
#include <cstddef>

// GCN: 4x GCNConv (512->256->128->64->32) + mean-pool + 2-layer MLP.
// Round 0: correct fp32 baseline.
//   - CSR built on-device per call (deterministic work), no float atomics.
//   - fp32 LDS-tiled GEMM for XW, separate gather-aggregate kernel.

// ---------------- CSR build ----------------

__global__ void k_count(const int* __restrict__ dst, int E, int* __restrict__ cnt) {
    int e = blockIdx.x * blockDim.x + threadIdx.x;
    if (e < E) atomicAdd(&cnt[dst[e]], 1);
}

__global__ void k_dinv(const int* __restrict__ cnt, int n, float* __restrict__ dinv) {
    int i = blockIdx.x * blockDim.x + threadIdx.x;
    if (i < n) dinv[i] = rsqrtf((float)(cnt[i] + 1));   // +1 self-loop; always > 0
}

// single-block exclusive scan of cnt -> row_ptr (row_ptr[n] = E)
__global__ void k_scan(const int* __restrict__ cnt, int n, int* __restrict__ row_ptr) {
    __shared__ int sums[1024];
    int tid = threadIdx.x;
    int per = (n + 1023) >> 10;
    int start = tid * per;
    int end = start + per; if (end > n) end = n; if (start > n) start = n;
    int s = 0;
    for (int i = start; i < end; ++i) s += cnt[i];
    sums[tid] = s;
    __syncthreads();
    for (int off = 1; off < 1024; off <<= 1) {
        int v = (tid >= off) ? sums[tid - off] : 0;
        __syncthreads();
        sums[tid] += v;
        __syncthreads();
    }
    int run = (tid == 0) ? 0 : sums[tid - 1];
    for (int i = start; i < end; ++i) { row_ptr[i] = run; run += cnt[i]; }
    if (tid == 0) row_ptr[n] = sums[1023];
}

__global__ void k_fill(const int* __restrict__ src, const int* __restrict__ dst, int E,
                       const int* __restrict__ row_ptr, int* __restrict__ cursor,
                       int* __restrict__ csr_src) {
    int e = blockIdx.x * blockDim.x + threadIdx.x;
    if (e >= E) return;
    int d = dst[e];
    int p = atomicAdd(&cursor[d], 1);
    csr_src[row_ptr[d] + p] = src[e];
}

// ---------------- fp32 tiled GEMM: C[M,N] = A[M,K] @ B[K,N] ----------------

template <int BM, int BN, int BK, int TM, int TN>
__global__ void k_gemm(const float* __restrict__ A, const float* __restrict__ B,
                       float* __restrict__ C, int M, int K, int N) {
    constexpr int THREADS = (BM / TM) * (BN / TN);
    __shared__ float As[BK][BM + 4];
    __shared__ float Bs[BK][BN];
    const int tid  = threadIdx.x;
    const int brow = blockIdx.y * BM;
    const int bcol = blockIdx.x * BN;
    const int tcol = tid % (BN / TN);
    const int trow = tid / (BN / TN);

    float acc[TM][TN];
#pragma unroll
    for (int i = 0; i < TM; ++i)
#pragma unroll
        for (int j = 0; j < TN; ++j) acc[i][j] = 0.f;

    for (int k0 = 0; k0 < K; k0 += BK) {
        // A tile (BM x BK): consecutive tid -> consecutive k (coalesced)
#pragma unroll
        for (int idx = tid; idx < BM * BK; idx += THREADS) {
            int m = idx / BK, kk = idx % BK;
            int gr = brow + m;
            As[kk][m] = (gr < M) ? A[(size_t)gr * K + k0 + kk] : 0.f;
        }
        // B tile (BK x BN): consecutive tid -> consecutive n (coalesced)
#pragma unroll
        for (int idx = tid; idx < BK * BN; idx += THREADS) {
            int kk = idx / BN, nn = idx % BN;
            Bs[kk][nn] = B[(size_t)(k0 + kk) * N + bcol + nn];
        }
        __syncthreads();
#pragma unroll
        for (int kk = 0; kk < BK; ++kk) {
            float a[TM], b[TN];
#pragma unroll
            for (int i = 0; i < TM; ++i) a[i] = As[kk][trow * TM + i];
#pragma unroll
            for (int j = 0; j < TN; ++j) b[j] = Bs[kk][tcol * TN + j];
#pragma unroll
            for (int i = 0; i < TM; ++i)
#pragma unroll
                for (int j = 0; j < TN; ++j) acc[i][j] += a[i] * b[j];
        }
        __syncthreads();
    }

#pragma unroll
    for (int i = 0; i < TM; ++i) {
        int gr = brow + trow * TM + i;
        if (gr >= M) continue;
#pragma unroll
        for (int j = 0; j < TN; ++j)
            C[(size_t)gr * N + bcol + tcol * TN + j] = acc[i][j];
    }
}

// ---------------- normalized aggregation (+bias, optional relu) ----------------
// out[i] = dinv[i] * ( sum_{s in N_in(i)} dinv[s]*h[s]  +  dinv[i]*h[i] ) + b

__global__ void k_agg(const float4* __restrict__ h, const int* __restrict__ row_ptr,
                      const int* __restrict__ csr_src, const float* __restrict__ dinv,
                      const float* __restrict__ bias, float4* __restrict__ out,
                      int n, int f_shift, int do_relu) {
    int idx = blockIdx.x * blockDim.x + threadIdx.x;
    int dout4 = 1 << f_shift;
    int total = n << f_shift;
    if (idx >= total) return;
    int i = idx >> f_shift;
    int f = idx & (dout4 - 1);

    float di = dinv[i];
    float4 hv = h[(size_t)i * dout4 + f];
    float4 acc;
    acc.x = hv.x * di; acc.y = hv.y * di; acc.z = hv.z * di; acc.w = hv.w * di;

    int s0 = row_ptr[i], s1 = row_ptr[i + 1];
    for (int e = s0; e < s1; ++e) {
        int s = csr_src[e];
        float ds = dinv[s];
        float4 v = h[(size_t)s * dout4 + f];
        acc.x += v.x * ds; acc.y += v.y * ds; acc.z += v.z * ds; acc.w += v.w * ds;
    }
    const float4* b4 = (const float4*)bias;
    float4 b = b4[f];
    float4 o;
    o.x = acc.x * di + b.x;
    o.y = acc.y * di + b.y;
    o.z = acc.z * di + b.z;
    o.w = acc.w * di + b.w;
    if (do_relu) {
        o.x = fmaxf(o.x, 0.f); o.y = fmaxf(o.y, 0.f);
        o.z = fmaxf(o.z, 0.f); o.w = fmaxf(o.w, 0.f);
    }
    out[(size_t)i * dout4 + f] = o;
}

// ---------------- mean pool per graph (batch sorted) ----------------

__global__ void k_pool(const float* __restrict__ h, const int* __restrict__ batch,
                       int n, float* __restrict__ pooled) {
    int g = blockIdx.x;
    // lower_bound(batch, key)
    int start, end;
    {
        int lo = 0, hi = n;
        while (lo < hi) { int mid = (lo + hi) >> 1; if (batch[mid] < g) lo = mid + 1; else hi = mid; }
        start = lo;
        lo = start; hi = n;
        while (lo < hi) { int mid = (lo + hi) >> 1; if (batch[mid] < g + 1) lo = mid + 1; else hi = mid; }
        end = lo;
    }
    int f = threadIdx.x & 31;
    int sub = threadIdx.x >> 5;        // 8 node-groups
    float s = 0.f;
    for (int i = start + sub; i < end; i += 8) s += h[(size_t)i * 32 + f];
    __shared__ float red[8][32];
    red[sub][f] = s;
    __syncthreads();
    if (sub == 0) {
        float t = 0.f;
#pragma unroll
        for (int k = 0; k < 8; ++k) t += red[k][f];
        int c = end - start;
        pooled[g * 32 + f] = t / (float)(c > 0 ? c : 1);
    }
}

// ---------------- tiny MLP head: relu(p@lw1+lb1)@lw2+lb2 ----------------

__global__ void k_mlp(const float* __restrict__ pooled, const float* __restrict__ lw1,
                      const float* __restrict__ lb1, const float* __restrict__ lw2,
                      const float* __restrict__ lb2, float* __restrict__ out, int g_count) {
    int g = threadIdx.x;
    if (g >= g_count) return;
    float p[32];
#pragma unroll
    for (int k = 0; k < 32; ++k) p[k] = pooled[g * 32 + k];
    float hmid[16];
#pragma unroll
    for (int j = 0; j < 16; ++j) {
        float s = lb1[j];
#pragma unroll
        for (int k = 0; k < 32; ++k) s += p[k] * lw1[k * 16 + j];
        hmid[j] = fmaxf(s, 0.f);
    }
#pragma unroll
    for (int o = 0; o < 2; ++o) {
        float s = lb2[o];
#pragma unroll
        for (int k = 0; k < 16; ++k) s += hmid[k] * lw2[k * 2 + o];
        out[g * 2 + o] = s;
    }
}

// ---------------- launch ----------------

extern "C" void kernel_launch(void* const* d_in, const int* in_sizes, int n_in,
                              void* d_out, int out_size, void* d_ws, size_t ws_size,
                              hipStream_t stream) {
    const float* x     = (const float*)d_in[0];
    const int*   ei    = (const int*)d_in[1];
    const int*   batch = (const int*)d_in[2];
    const float* w1 = (const float*)d_in[3];  const float* b1 = (const float*)d_in[4];
    const float* w2 = (const float*)d_in[5];  const float* b2 = (const float*)d_in[6];
    const float* w3 = (const float*)d_in[7];  const float* b3 = (const float*)d_in[8];
    const float* w4 = (const float*)d_in[9];  const float* b4 = (const float*)d_in[10];
    const float* lw1 = (const float*)d_in[11]; const float* lb1 = (const float*)d_in[12];
    const float* lw2 = (const float*)d_in[13]; const float* lb2 = (const float*)d_in[14];
    float* out = (float*)d_out;

    const int n = in_sizes[0] / 512;   // 100000
    const int E = in_sizes[1] / 2;     // 320000
    const int G = 64;

    const int* src = ei;
    const int* dst = ei + E;

    // workspace layout (≈208 MB)
    char* ws = (char*)d_ws;
    size_t off = 0;
    auto alloc = [&](size_t bytes) -> void* {
        void* p = ws + off;
        off = (off + bytes + 255) & ~((size_t)255);
        return p;
    };
    float* bufA    = (float*)alloc((size_t)n * 256 * sizeof(float));
    float* bufB    = (float*)alloc((size_t)n * 256 * sizeof(float));
    int*   cnt     = (int*)alloc((size_t)n * sizeof(int));
    int*   row_ptr = (int*)alloc((size_t)(n + 1) * sizeof(int));
    int*   cursor  = (int*)alloc((size_t)n * sizeof(int));
    int*   csr     = (int*)alloc((size_t)E * sizeof(int));
    float* dinv    = (float*)alloc((size_t)n * sizeof(float));
    float* pooled  = (float*)alloc((size_t)G * 32 * sizeof(float));
    (void)ws_size;

    hipMemsetAsync(cnt, 0, (size_t)n * sizeof(int), stream);
    hipMemsetAsync(cursor, 0, (size_t)n * sizeof(int), stream);

    k_count<<<(E + 255) / 256, 256, 0, stream>>>(dst, E, cnt);
    k_dinv <<<(n + 255) / 256, 256, 0, stream>>>(cnt, n, dinv);
    k_scan <<<1, 1024, 0, stream>>>(cnt, n, row_ptr);
    k_fill <<<(E + 255) / 256, 256, 0, stream>>>(src, dst, E, row_ptr, cursor, csr);

    const int gy = (n + 127) / 128;

    // layer 1: [n,512]@[512,256]
    k_gemm<128, 64, 16, 8, 4><<<dim3(256 / 64, gy), 256, 0, stream>>>(x, w1, bufA, n, 512, 256);
    k_agg<<<((size_t)n * 64 + 255) / 256, 256, 0, stream>>>(
        (const float4*)bufA, row_ptr, csr, dinv, b1, (float4*)bufB, n, 6, 1);

    // layer 2: [n,256]@[256,128]
    k_gemm<128, 64, 16, 8, 4><<<dim3(128 / 64, gy), 256, 0, stream>>>(bufB, w2, bufA, n, 256, 128);
    k_agg<<<((size_t)n * 32 + 255) / 256, 256, 0, stream>>>(
        (const float4*)bufA, row_ptr, csr, dinv, b2, (float4*)bufB, n, 5, 1);

    // layer 3: [n,128]@[128,64]
    k_gemm<128, 64, 16, 8, 4><<<dim3(1, gy), 256, 0, stream>>>(bufB, w3, bufA, n, 128, 64);
    k_agg<<<((size_t)n * 16 + 255) / 256, 256, 0, stream>>>(
        (const float4*)bufA, row_ptr, csr, dinv, b3, (float4*)bufB, n, 4, 1);

    // layer 4: [n,64]@[64,32]  (no relu after aggregate)
    k_gemm<128, 32, 16, 8, 4><<<dim3(1, gy), 128, 0, stream>>>(bufB, w4, bufA, n, 64, 32);
    k_agg<<<((size_t)n * 8 + 255) / 256, 256, 0, stream>>>(
        (const float4*)bufA, row_ptr, csr, dinv, b4, (float4*)bufB, n, 3, 0);

    k_pool<<<G, 256, 0, stream>>>(bufB, batch, n, pooled);
    k_mlp<<<1, 64, 0, stream>>>(pooled, lw1, lb1, lw2, lb2, out, G);
}

// Round 2
// 658.945 us; speedup vs baseline: 1.8397x; 1.8397x over previous
//
#include <hip/hip_runtime.h>
#include <cstdint>
#include <cstddef>

// GCN: 4x GCNConv (512->256->128->64->32) + mean-pool + 2-layer MLP.
// Round 2: split-bf16 MFMA GEMM (hi/lo decomposition, 3-product) replaces
// fp32 VALU GEMM. CSR aggregation unchanged.

typedef __attribute__((ext_vector_type(8))) short s16x8;
typedef __attribute__((ext_vector_type(4))) float f32x4;

// fp32 -> (bf16 hi, bf16 lo) by truncation; lo captures the truncation error.
__device__ __forceinline__ short2 split2(float f) {
    union { float f; unsigned u; } c; c.f = f;
    short hi = (short)(c.u >> 16);
    union { unsigned u; float f; } h; h.u = c.u & 0xffff0000u;
    union { float f; unsigned u; } r; r.f = f - h.f;
    short lo = (short)(r.u >> 16);
    return make_short2(hi, lo);
}

// ---------------- CSR build ----------------

__global__ void k_count(const int* __restrict__ dst, int E, int* __restrict__ cnt) {
    int e = blockIdx.x * blockDim.x + threadIdx.x;
    if (e < E) atomicAdd(&cnt[dst[e]], 1);
}

__global__ void k_dinv(const int* __restrict__ cnt, int n, float* __restrict__ dinv) {
    int i = blockIdx.x * blockDim.x + threadIdx.x;
    if (i < n) dinv[i] = rsqrtf((float)(cnt[i] + 1));
}

__global__ void k_scan(const int* __restrict__ cnt, int n, int* __restrict__ row_ptr) {
    __shared__ int sums[1024];
    int tid = threadIdx.x;
    int per = (n + 1023) >> 10;
    int start = tid * per;
    int end = start + per; if (end > n) end = n; if (start > n) start = n;
    int s = 0;
    for (int i = start; i < end; ++i) s += cnt[i];
    sums[tid] = s;
    __syncthreads();
    for (int off = 1; off < 1024; off <<= 1) {
        int v = (tid >= off) ? sums[tid - off] : 0;
        __syncthreads();
        sums[tid] += v;
        __syncthreads();
    }
    int run = (tid == 0) ? 0 : sums[tid - 1];
    for (int i = start; i < end; ++i) { row_ptr[i] = run; run += cnt[i]; }
    if (tid == 0) row_ptr[n] = sums[1023];
}

__global__ void k_fill(const int* __restrict__ src, const int* __restrict__ dst, int E,
                       const int* __restrict__ row_ptr, int* __restrict__ cursor,
                       int* __restrict__ csr_src) {
    int e = blockIdx.x * blockDim.x + threadIdx.x;
    if (e >= E) return;
    int d = dst[e];
    int p = atomicAdd(&cursor[d], 1);
    csr_src[row_ptr[d] + p] = src[e];
}

// ---------------- split-bf16 MFMA GEMM: C[M,N] = A[M,K] @ B[K,N] ----------------
// Tiles: BM = GM*FM*16, BN = GN*FN*16, BK = 32. 256 threads = 4 waves (GM*GN).
// LDS: A and B staged as (row/col)-major x K-contiguous bf16, hi and lo planes,
// XOR-swizzled byte ^= ((row&7)<<4) so ds_read_b128 is conflict-free.

#define SWZ(row, kbyte) ((((row) * 64)) ^ (kbyte) ^ (((row) & 7) << 4))

template <int FM, int FN, int GM, int GN>
__global__ __launch_bounds__(256)
void k_gemm_mfma(const float* __restrict__ A, const float* __restrict__ B,
                 float* __restrict__ C, int M, int K, int N) {
    constexpr int BM = GM * FM * 16;
    constexpr int BN = GN * FN * 16;
    constexpr int BK = 32;
    constexpr int ASZ = BM * BK * 2;   // bytes, bf16 plane
    constexpr int BSZ = BN * BK * 2;
    __shared__ char lds[2 * ASZ + 2 * BSZ];
    char* sAh = lds;
    char* sAl = lds + ASZ;
    char* sBh = lds + 2 * ASZ;
    char* sBl = lds + 2 * ASZ + BSZ;

    const int tid  = threadIdx.x;
    const int lane = tid & 63;
    const int wid  = tid >> 6;
    const int wm   = wid % GM;
    const int wn   = wid / GM;
    const int brow = blockIdx.y * BM;
    const int bcol = blockIdx.x * BN;
    const int l15  = lane & 15;
    const int kb   = ((lane >> 4) * 8) * 2;  // this lane's k-slice byte offset

    f32x4 acc[FM][FN];
#pragma unroll
    for (int i = 0; i < FM; ++i)
#pragma unroll
        for (int j = 0; j < FN; ++j) acc[i][j] = (f32x4){0.f, 0.f, 0.f, 0.f};

    for (int k0 = 0; k0 < K; k0 += BK) {
        // ---- stage A (BM x BK): thread -> (row, half of K) ----
#pragma unroll
        for (int slot = tid; slot < BM * 2; slot += 256) {
            int row = slot >> 1, half = slot & 1;
            int gr = brow + row;
            float4 v0, v1, v2, v3;
            if (gr < M) {
                const float4* ap = (const float4*)(A + (size_t)gr * K + k0 + half * 16);
                v0 = ap[0]; v1 = ap[1]; v2 = ap[2]; v3 = ap[3];
            } else {
                v0 = v1 = v2 = v3 = make_float4(0.f, 0.f, 0.f, 0.f);
            }
            s16x8 h0, h1, l0, l1;
            short2 p;
            p = split2(v0.x); h0[0] = p.x; l0[0] = p.y;
            p = split2(v0.y); h0[1] = p.x; l0[1] = p.y;
            p = split2(v0.z); h0[2] = p.x; l0[2] = p.y;
            p = split2(v0.w); h0[3] = p.x; l0[3] = p.y;
            p = split2(v1.x); h0[4] = p.x; l0[4] = p.y;
            p = split2(v1.y); h0[5] = p.x; l0[5] = p.y;
            p = split2(v1.z); h0[6] = p.x; l0[6] = p.y;
            p = split2(v1.w); h0[7] = p.x; l0[7] = p.y;
            p = split2(v2.x); h1[0] = p.x; l1[0] = p.y;
            p = split2(v2.y); h1[1] = p.x; l1[1] = p.y;
            p = split2(v2.z); h1[2] = p.x; l1[2] = p.y;
            p = split2(v2.w); h1[3] = p.x; l1[3] = p.y;
            p = split2(v3.x); h1[4] = p.x; l1[4] = p.y;
            p = split2(v3.y); h1[5] = p.x; l1[5] = p.y;
            p = split2(v3.z); h1[6] = p.x; l1[6] = p.y;
            p = split2(v3.w); h1[7] = p.x; l1[7] = p.y;
            int base = half * 32;
            *(s16x8*)(sAh + SWZ(row, base))      = h0;
            *(s16x8*)(sAh + SWZ(row, base + 16)) = h1;
            *(s16x8*)(sAl + SWZ(row, base))      = l0;
            *(s16x8*)(sAl + SWZ(row, base + 16)) = l1;
        }
        // ---- stage B transposed (BN cols x BK): thread -> (col, half of K) ----
#pragma unroll
        for (int slot = tid; slot < BN * 2; slot += 256) {
            int col = slot >> 1, half = slot & 1;
            const float* bp = B + (size_t)(k0 + half * 16) * N + bcol + col;
            s16x8 h0, h1, l0, l1;
#pragma unroll
            for (int j = 0; j < 8; ++j) {
                short2 p = split2(bp[(size_t)j * N]);
                h0[j] = p.x; l0[j] = p.y;
            }
#pragma unroll
            for (int j = 0; j < 8; ++j) {
                short2 p = split2(bp[(size_t)(8 + j) * N]);
                h1[j] = p.x; l1[j] = p.y;
            }
            int base = half * 32;
            *(s16x8*)(sBh + SWZ(col, base))      = h0;
            *(s16x8*)(sBh + SWZ(col, base + 16)) = h1;
            *(s16x8*)(sBl + SWZ(col, base))      = l0;
            *(s16x8*)(sBl + SWZ(col, base + 16)) = l1;
        }
        __syncthreads();

        // ---- fragments + MFMA (3-product split accumulation) ----
        s16x8 ah[FM], am[FM], bh[FN], bm[FN];
#pragma unroll
        for (int i = 0; i < FM; ++i) {
            int row = wm * FM * 16 + i * 16 + l15;
            ah[i] = *(const s16x8*)(sAh + SWZ(row, kb));
            am[i] = *(const s16x8*)(sAl + SWZ(row, kb));
        }
#pragma unroll
        for (int j = 0; j < FN; ++j) {
            int col = wn * FN * 16 + j * 16 + l15;
            bh[j] = *(const s16x8*)(sBh + SWZ(col, kb));
            bm[j] = *(const s16x8*)(sBl + SWZ(col, kb));
        }
#pragma unroll
        for (int i = 0; i < FM; ++i)
#pragma unroll
            for (int j = 0; j < FN; ++j) {
                acc[i][j] = __builtin_amdgcn_mfma_f32_16x16x32_bf16(ah[i], bh[j], acc[i][j], 0, 0, 0);
                acc[i][j] = __builtin_amdgcn_mfma_f32_16x16x32_bf16(am[i], bh[j], acc[i][j], 0, 0, 0);
                acc[i][j] = __builtin_amdgcn_mfma_f32_16x16x32_bf16(ah[i], bm[j], acc[i][j], 0, 0, 0);
            }
        __syncthreads();
    }

    // ---- store: C/D layout col=lane&15, row=(lane>>4)*4+reg ----
#pragma unroll
    for (int i = 0; i < FM; ++i) {
#pragma unroll
        for (int r = 0; r < 4; ++r) {
            int row = brow + wm * FM * 16 + i * 16 + (lane >> 4) * 4 + r;
            if (row >= M) continue;
#pragma unroll
            for (int j = 0; j < FN; ++j) {
                int col = bcol + wn * FN * 16 + j * 16 + l15;
                C[(size_t)row * N + col] = acc[i][j][r];
            }
        }
    }
}

// ---------------- normalized aggregation (+bias, optional relu) ----------------

__global__ void k_agg(const float4* __restrict__ h, const int* __restrict__ row_ptr,
                      const int* __restrict__ csr_src, const float* __restrict__ dinv,
                      const float* __restrict__ bias, float4* __restrict__ out,
                      int n, int f_shift, int do_relu) {
    int idx = blockIdx.x * blockDim.x + threadIdx.x;
    int dout4 = 1 << f_shift;
    int total = n << f_shift;
    if (idx >= total) return;
    int i = idx >> f_shift;
    int f = idx & (dout4 - 1);

    float di = dinv[i];
    float4 hv = h[(size_t)i * dout4 + f];
    float4 acc;
    acc.x = hv.x * di; acc.y = hv.y * di; acc.z = hv.z * di; acc.w = hv.w * di;

    int s0 = row_ptr[i], s1 = row_ptr[i + 1];
    for (int e = s0; e < s1; ++e) {
        int s = csr_src[e];
        float ds = dinv[s];
        float4 v = h[(size_t)s * dout4 + f];
        acc.x += v.x * ds; acc.y += v.y * ds; acc.z += v.z * ds; acc.w += v.w * ds;
    }
    const float4* b4 = (const float4*)bias;
    float4 b = b4[f];
    float4 o;
    o.x = acc.x * di + b.x;
    o.y = acc.y * di + b.y;
    o.z = acc.z * di + b.z;
    o.w = acc.w * di + b.w;
    if (do_relu) {
        o.x = fmaxf(o.x, 0.f); o.y = fmaxf(o.y, 0.f);
        o.z = fmaxf(o.z, 0.f); o.w = fmaxf(o.w, 0.f);
    }
    out[(size_t)i * dout4 + f] = o;
}

// ---------------- mean pool per graph (batch sorted) ----------------

__global__ void k_pool(const float* __restrict__ h, const int* __restrict__ batch,
                       int n, float* __restrict__ pooled) {
    int g = blockIdx.x;
    int start, end;
    {
        int lo = 0, hi = n;
        while (lo < hi) { int mid = (lo + hi) >> 1; if (batch[mid] < g) lo = mid + 1; else hi = mid; }
        start = lo;
        lo = start; hi = n;
        while (lo < hi) { int mid = (lo + hi) >> 1; if (batch[mid] < g + 1) lo = mid + 1; else hi = mid; }
        end = lo;
    }
    int f = threadIdx.x & 31;
    int sub = threadIdx.x >> 5;
    float s = 0.f;
    for (int i = start + sub; i < end; i += 8) s += h[(size_t)i * 32 + f];
    __shared__ float red[8][32];
    red[sub][f] = s;
    __syncthreads();
    if (sub == 0) {
        float t = 0.f;
#pragma unroll
        for (int k = 0; k < 8; ++k) t += red[k][f];
        int c = end - start;
        pooled[g * 32 + f] = t / (float)(c > 0 ? c : 1);
    }
}

// ---------------- tiny MLP head ----------------

__global__ void k_mlp(const float* __restrict__ pooled, const float* __restrict__ lw1,
                      const float* __restrict__ lb1, const float* __restrict__ lw2,
                      const float* __restrict__ lb2, float* __restrict__ out, int g_count) {
    int g = threadIdx.x;
    if (g >= g_count) return;
    float p[32];
#pragma unroll
    for (int k = 0; k < 32; ++k) p[k] = pooled[g * 32 + k];
    float hmid[16];
#pragma unroll
    for (int j = 0; j < 16; ++j) {
        float s = lb1[j];
#pragma unroll
        for (int k = 0; k < 32; ++k) s += p[k] * lw1[k * 16 + j];
        hmid[j] = fmaxf(s, 0.f);
    }
#pragma unroll
    for (int o = 0; o < 2; ++o) {
        float s = lb2[o];
#pragma unroll
        for (int k = 0; k < 16; ++k) s += hmid[k] * lw2[k * 2 + o];
        out[g * 2 + o] = s;
    }
}

// ---------------- launch ----------------

extern "C" void kernel_launch(void* const* d_in, const int* in_sizes, int n_in,
                              void* d_out, int out_size, void* d_ws, size_t ws_size,
                              hipStream_t stream) {
    const float* x     = (const float*)d_in[0];
    const int*   ei    = (const int*)d_in[1];
    const int*   batch = (const int*)d_in[2];
    const float* w1 = (const float*)d_in[3];  const float* b1 = (const float*)d_in[4];
    const float* w2 = (const float*)d_in[5];  const float* b2 = (const float*)d_in[6];
    const float* w3 = (const float*)d_in[7];  const float* b3 = (const float*)d_in[8];
    const float* w4 = (const float*)d_in[9];  const float* b4 = (const float*)d_in[10];
    const float* lw1 = (const float*)d_in[11]; const float* lb1 = (const float*)d_in[12];
    const float* lw2 = (const float*)d_in[13]; const float* lb2 = (const float*)d_in[14];
    float* out = (float*)d_out;

    const int n = in_sizes[0] / 512;   // 100000
    const int E = in_sizes[1] / 2;     // 320000
    const int G = 64;

    const int* src = ei;
    const int* dst = ei + E;

    char* ws = (char*)d_ws;
    size_t off = 0;
    auto alloc = [&](size_t bytes) -> void* {
        void* p = ws + off;
        off = (off + bytes + 255) & ~((size_t)255);
        return p;
    };
    float* bufA    = (float*)alloc((size_t)n * 256 * sizeof(float));
    float* bufB    = (float*)alloc((size_t)n * 256 * sizeof(float));
    int*   cnt     = (int*)alloc((size_t)n * sizeof(int));
    int*   row_ptr = (int*)alloc((size_t)(n + 1) * sizeof(int));
    int*   cursor  = (int*)alloc((size_t)n * sizeof(int));
    int*   csr     = (int*)alloc((size_t)E * sizeof(int));
    float* dinv    = (float*)alloc((size_t)n * sizeof(float));
    float* pooled  = (float*)alloc((size_t)G * 32 * sizeof(float));
    (void)ws_size;

    hipMemsetAsync(cnt, 0, (size_t)n * sizeof(int), stream);
    hipMemsetAsync(cursor, 0, (size_t)n * sizeof(int), stream);

    k_count<<<(E + 255) / 256, 256, 0, stream>>>(dst, E, cnt);
    k_dinv <<<(n + 255) / 256, 256, 0, stream>>>(cnt, n, dinv);
    k_scan <<<1, 1024, 0, stream>>>(cnt, n, row_ptr);
    k_fill <<<(E + 255) / 256, 256, 0, stream>>>(src, dst, E, row_ptr, cursor, csr);

    const int gy = (n + 127) / 128;   // BM = 128 for all layers

    // layer 1: [n,512]@[512,256]  BN=128
    k_gemm_mfma<4, 4, 2, 2><<<dim3(2, gy), 256, 0, stream>>>(x, w1, bufA, n, 512, 256);
    k_agg<<<((size_t)n * 64 + 255) / 256, 256, 0, stream>>>(
        (const float4*)bufA, row_ptr, csr, dinv, b1, (float4*)bufB, n, 6, 1);

    // layer 2: [n,256]@[256,128]  BN=128
    k_gemm_mfma<4, 4, 2, 2><<<dim3(1, gy), 256, 0, stream>>>(bufB, w2, bufA, n, 256, 128);
    k_agg<<<((size_t)n * 32 + 255) / 256, 256, 0, stream>>>(
        (const float4*)bufA, row_ptr, csr, dinv, b2, (float4*)bufB, n, 5, 1);

    // layer 3: [n,128]@[128,64]  BN=64
    k_gemm_mfma<4, 2, 2, 2><<<dim3(1, gy), 256, 0, stream>>>(bufB, w3, bufA, n, 128, 64);
    k_agg<<<((size_t)n * 16 + 255) / 256, 256, 0, stream>>>(
        (const float4*)bufA, row_ptr, csr, dinv, b3, (float4*)bufB, n, 4, 1);

    // layer 4: [n,64]@[64,32]  BN=32 (no relu)
    k_gemm_mfma<2, 2, 4, 1><<<dim3(1, gy), 256, 0, stream>>>(bufB, w4, bufA, n, 64, 32);
    k_agg<<<((size_t)n * 8 + 255) / 256, 256, 0, stream>>>(
        (const float4*)bufA, row_ptr, csr, dinv, b4, (float4*)bufB, n, 3, 0);

    k_pool<<<G, 256, 0, stream>>>(bufB, batch, n, pooled);
    k_mlp<<<1, 64, 0, stream>>>(pooled, lw1, lb1, lw2, lb2, out, G);
}

// Round 3
// 509.493 us; speedup vs baseline: 2.3794x; 1.2933x over previous
//
#include <hip/hip_runtime.h>
#include <cstdint>
#include <cstddef>

// GCN: 4x GCNConv (512->256->128->64->32) + mean-pool + 2-layer MLP.
// Round 3: replace 164us single-block scan with 3-pass multi-block scan.
// Split-bf16 MFMA GEMM and CSR aggregation unchanged.

typedef __attribute__((ext_vector_type(8))) short s16x8;
typedef __attribute__((ext_vector_type(4))) float f32x4;

// fp32 -> (bf16 hi, bf16 lo) by truncation; lo captures the truncation error.
__device__ __forceinline__ short2 split2(float f) {
    union { float f; unsigned u; } c; c.f = f;
    short hi = (short)(c.u >> 16);
    union { unsigned u; float f; } h; h.u = c.u & 0xffff0000u;
    union { float f; unsigned u; } r; r.f = f - h.f;
    short lo = (short)(r.u >> 16);
    return make_short2(hi, lo);
}

// ---------------- CSR build ----------------

__global__ void k_count(const int* __restrict__ dst, int E, int* __restrict__ cnt) {
    int e = blockIdx.x * blockDim.x + threadIdx.x;
    if (e < E) atomicAdd(&cnt[dst[e]], 1);
}

__global__ void k_dinv(const int* __restrict__ cnt, int n, float* __restrict__ dinv) {
    int i = blockIdx.x * blockDim.x + threadIdx.x;
    if (i < n) dinv[i] = rsqrtf((float)(cnt[i] + 1));
}

// ---- 3-pass scan: 4096 elements per block (256 threads x 16) ----

__global__ void k_scan_sums(const int* __restrict__ cnt, int n, int* __restrict__ bsum) {
    __shared__ int s[256];
    int t = threadIdx.x;
    int base = blockIdx.x * 4096 + t * 16;
    int sum = 0;
#pragma unroll
    for (int j = 0; j < 16; ++j) { int i = base + j; if (i < n) sum += cnt[i]; }
    s[t] = sum;
    __syncthreads();
    for (int off = 128; off > 0; off >>= 1) {
        if (t < off) s[t] += s[t + off];
        __syncthreads();
    }
    if (t == 0) bsum[blockIdx.x] = s[0];
}

// single wave: exclusive scan of nb (<=64) block sums; total -> *totalp
__global__ void k_scan_offsets(const int* __restrict__ bsum, int nb,
                               int* __restrict__ boff, int* __restrict__ totalp) {
    int t = threadIdx.x;   // 64 threads
    int v = (t < nb) ? bsum[t] : 0;
    int x = v;
    for (int off = 1; off < 64; off <<= 1) {
        int y = __shfl_up(x, off);
        if (t >= off) x += y;
    }
    if (t < nb) boff[t] = x - v;        // exclusive
    if (t == 63) *totalp = x;           // grand total (= E)
}

__global__ void k_scan_final(const int* __restrict__ cnt, int n,
                             const int* __restrict__ boff, int* __restrict__ row_ptr) {
    __shared__ int s[256];
    int t = threadIdx.x;
    int base = blockIdx.x * 4096 + t * 16;
    int v[16]; int sum = 0;
#pragma unroll
    for (int j = 0; j < 16; ++j) { int i = base + j; v[j] = (i < n) ? cnt[i] : 0; sum += v[j]; }
    s[t] = sum;
    __syncthreads();
    for (int off = 1; off < 256; off <<= 1) {
        int y = (t >= off) ? s[t - off] : 0;
        __syncthreads();
        s[t] += y;
        __syncthreads();
    }
    int run = boff[blockIdx.x] + ((t == 0) ? 0 : s[t - 1]);
#pragma unroll
    for (int j = 0; j < 16; ++j) {
        int i = base + j;
        if (i < n) row_ptr[i] = run;
        run += v[j];
    }
}

__global__ void k_fill(const int* __restrict__ src, const int* __restrict__ dst, int E,
                       const int* __restrict__ row_ptr, int* __restrict__ cursor,
                       int* __restrict__ csr_src) {
    int e = blockIdx.x * blockDim.x + threadIdx.x;
    if (e >= E) return;
    int d = dst[e];
    int p = atomicAdd(&cursor[d], 1);
    csr_src[row_ptr[d] + p] = src[e];
}

// ---------------- split-bf16 MFMA GEMM: C[M,N] = A[M,K] @ B[K,N] ----------------

#define SWZ(row, kbyte) ((((row) * 64)) ^ (kbyte) ^ (((row) & 7) << 4))

template <int FM, int FN, int GM, int GN>
__global__ __launch_bounds__(256)
void k_gemm_mfma(const float* __restrict__ A, const float* __restrict__ B,
                 float* __restrict__ C, int M, int K, int N) {
    constexpr int BM = GM * FM * 16;
    constexpr int BN = GN * FN * 16;
    constexpr int BK = 32;
    constexpr int ASZ = BM * BK * 2;   // bytes, bf16 plane
    constexpr int BSZ = BN * BK * 2;
    __shared__ char lds[2 * ASZ + 2 * BSZ];
    char* sAh = lds;
    char* sAl = lds + ASZ;
    char* sBh = lds + 2 * ASZ;
    char* sBl = lds + 2 * ASZ + BSZ;

    const int tid  = threadIdx.x;
    const int lane = tid & 63;
    const int wid  = tid >> 6;
    const int wm   = wid % GM;
    const int wn   = wid / GM;
    const int brow = blockIdx.y * BM;
    const int bcol = blockIdx.x * BN;
    const int l15  = lane & 15;
    const int kb   = ((lane >> 4) * 8) * 2;  // this lane's k-slice byte offset

    f32x4 acc[FM][FN];
#pragma unroll
    for (int i = 0; i < FM; ++i)
#pragma unroll
        for (int j = 0; j < FN; ++j) acc[i][j] = (f32x4){0.f, 0.f, 0.f, 0.f};

    for (int k0 = 0; k0 < K; k0 += BK) {
        // ---- stage A (BM x BK): thread -> (row, half of K) ----
#pragma unroll
        for (int slot = tid; slot < BM * 2; slot += 256) {
            int row = slot >> 1, half = slot & 1;
            int gr = brow + row;
            float4 v0, v1, v2, v3;
            if (gr < M) {
                const float4* ap = (const float4*)(A + (size_t)gr * K + k0 + half * 16);
                v0 = ap[0]; v1 = ap[1]; v2 = ap[2]; v3 = ap[3];
            } else {
                v0 = v1 = v2 = v3 = make_float4(0.f, 0.f, 0.f, 0.f);
            }
            s16x8 h0, h1, l0, l1;
            short2 p;
            p = split2(v0.x); h0[0] = p.x; l0[0] = p.y;
            p = split2(v0.y); h0[1] = p.x; l0[1] = p.y;
            p = split2(v0.z); h0[2] = p.x; l0[2] = p.y;
            p = split2(v0.w); h0[3] = p.x; l0[3] = p.y;
            p = split2(v1.x); h0[4] = p.x; l0[4] = p.y;
            p = split2(v1.y); h0[5] = p.x; l0[5] = p.y;
            p = split2(v1.z); h0[6] = p.x; l0[6] = p.y;
            p = split2(v1.w); h0[7] = p.x; l0[7] = p.y;
            p = split2(v2.x); h1[0] = p.x; l1[0] = p.y;
            p = split2(v2.y); h1[1] = p.x; l1[1] = p.y;
            p = split2(v2.z); h1[2] = p.x; l1[2] = p.y;
            p = split2(v2.w); h1[3] = p.x; l1[3] = p.y;
            p = split2(v3.x); h1[4] = p.x; l1[4] = p.y;
            p = split2(v3.y); h1[5] = p.x; l1[5] = p.y;
            p = split2(v3.z); h1[6] = p.x; l1[6] = p.y;
            p = split2(v3.w); h1[7] = p.x; l1[7] = p.y;
            int base = half * 32;
            *(s16x8*)(sAh + SWZ(row, base))      = h0;
            *(s16x8*)(sAh + SWZ(row, base + 16)) = h1;
            *(s16x8*)(sAl + SWZ(row, base))      = l0;
            *(s16x8*)(sAl + SWZ(row, base + 16)) = l1;
        }
        // ---- stage B transposed (BN cols x BK): thread -> (col, half of K) ----
#pragma unroll
        for (int slot = tid; slot < BN * 2; slot += 256) {
            int col = slot >> 1, half = slot & 1;
            const float* bp = B + (size_t)(k0 + half * 16) * N + bcol + col;
            s16x8 h0, h1, l0, l1;
#pragma unroll
            for (int j = 0; j < 8; ++j) {
                short2 p = split2(bp[(size_t)j * N]);
                h0[j] = p.x; l0[j] = p.y;
            }
#pragma unroll
            for (int j = 0; j < 8; ++j) {
                short2 p = split2(bp[(size_t)(8 + j) * N]);
                h1[j] = p.x; l1[j] = p.y;
            }
            int base = half * 32;
            *(s16x8*)(sBh + SWZ(col, base))      = h0;
            *(s16x8*)(sBh + SWZ(col, base + 16)) = h1;
            *(s16x8*)(sBl + SWZ(col, base))      = l0;
            *(s16x8*)(sBl + SWZ(col, base + 16)) = l1;
        }
        __syncthreads();

        // ---- fragments + MFMA (3-product split accumulation) ----
        s16x8 ah[FM], am[FM], bh[FN], bm[FN];
#pragma unroll
        for (int i = 0; i < FM; ++i) {
            int row = wm * FM * 16 + i * 16 + l15;
            ah[i] = *(const s16x8*)(sAh + SWZ(row, kb));
            am[i] = *(const s16x8*)(sAl + SWZ(row, kb));
        }
#pragma unroll
        for (int j = 0; j < FN; ++j) {
            int col = wn * FN * 16 + j * 16 + l15;
            bh[j] = *(const s16x8*)(sBh + SWZ(col, kb));
            bm[j] = *(const s16x8*)(sBl + SWZ(col, kb));
        }
#pragma unroll
        for (int i = 0; i < FM; ++i)
#pragma unroll
            for (int j = 0; j < FN; ++j) {
                acc[i][j] = __builtin_amdgcn_mfma_f32_16x16x32_bf16(ah[i], bh[j], acc[i][j], 0, 0, 0);
                acc[i][j] = __builtin_amdgcn_mfma_f32_16x16x32_bf16(am[i], bh[j], acc[i][j], 0, 0, 0);
                acc[i][j] = __builtin_amdgcn_mfma_f32_16x16x32_bf16(ah[i], bm[j], acc[i][j], 0, 0, 0);
            }
        __syncthreads();
    }

    // ---- store: C/D layout col=lane&15, row=(lane>>4)*4+reg ----
#pragma unroll
    for (int i = 0; i < FM; ++i) {
#pragma unroll
        for (int r = 0; r < 4; ++r) {
            int row = brow + wm * FM * 16 + i * 16 + (lane >> 4) * 4 + r;
            if (row >= M) continue;
#pragma unroll
            for (int j = 0; j < FN; ++j) {
                int col = bcol + wn * FN * 16 + j * 16 + l15;
                C[(size_t)row * N + col] = acc[i][j][r];
            }
        }
    }
}

// ---------------- normalized aggregation (+bias, optional relu) ----------------

__global__ void k_agg(const float4* __restrict__ h, const int* __restrict__ row_ptr,
                      const int* __restrict__ csr_src, const float* __restrict__ dinv,
                      const float* __restrict__ bias, float4* __restrict__ out,
                      int n, int f_shift, int do_relu) {
    int idx = blockIdx.x * blockDim.x + threadIdx.x;
    int dout4 = 1 << f_shift;
    int total = n << f_shift;
    if (idx >= total) return;
    int i = idx >> f_shift;
    int f = idx & (dout4 - 1);

    float di = dinv[i];
    float4 hv = h[(size_t)i * dout4 + f];
    float4 acc;
    acc.x = hv.x * di; acc.y = hv.y * di; acc.z = hv.z * di; acc.w = hv.w * di;

    int s0 = row_ptr[i], s1 = row_ptr[i + 1];
    for (int e = s0; e < s1; ++e) {
        int s = csr_src[e];
        float ds = dinv[s];
        float4 v = h[(size_t)s * dout4 + f];
        acc.x += v.x * ds; acc.y += v.y * ds; acc.z += v.z * ds; acc.w += v.w * ds;
    }
    const float4* b4 = (const float4*)bias;
    float4 b = b4[f];
    float4 o;
    o.x = acc.x * di + b.x;
    o.y = acc.y * di + b.y;
    o.z = acc.z * di + b.z;
    o.w = acc.w * di + b.w;
    if (do_relu) {
        o.x = fmaxf(o.x, 0.f); o.y = fmaxf(o.y, 0.f);
        o.z = fmaxf(o.z, 0.f); o.w = fmaxf(o.w, 0.f);
    }
    out[(size_t)i * dout4 + f] = o;
}

// ---------------- mean pool per graph (batch sorted) ----------------

__global__ void k_pool(const float* __restrict__ h, const int* __restrict__ batch,
                       int n, float* __restrict__ pooled) {
    int g = blockIdx.x;
    int start, end;
    {
        int lo = 0, hi = n;
        while (lo < hi) { int mid = (lo + hi) >> 1; if (batch[mid] < g) lo = mid + 1; else hi = mid; }
        start = lo;
        lo = start; hi = n;
        while (lo < hi) { int mid = (lo + hi) >> 1; if (batch[mid] < g + 1) lo = mid + 1; else hi = mid; }
        end = lo;
    }
    int f = threadIdx.x & 31;
    int sub = threadIdx.x >> 5;
    float s = 0.f;
    for (int i = start + sub; i < end; i += 8) s += h[(size_t)i * 32 + f];
    __shared__ float red[8][32];
    red[sub][f] = s;
    __syncthreads();
    if (sub == 0) {
        float t = 0.f;
#pragma unroll
        for (int k = 0; k < 8; ++k) t += red[k][f];
        int c = end - start;
        pooled[g * 32 + f] = t / (float)(c > 0 ? c : 1);
    }
}

// ---------------- tiny MLP head ----------------

__global__ void k_mlp(const float* __restrict__ pooled, const float* __restrict__ lw1,
                      const float* __restrict__ lb1, const float* __restrict__ lw2,
                      const float* __restrict__ lb2, float* __restrict__ out, int g_count) {
    int g = threadIdx.x;
    if (g >= g_count) return;
    float p[32];
#pragma unroll
    for (int k = 0; k < 32; ++k) p[k] = pooled[g * 32 + k];
    float hmid[16];
#pragma unroll
    for (int j = 0; j < 16; ++j) {
        float s = lb1[j];
#pragma unroll
        for (int k = 0; k < 32; ++k) s += p[k] * lw1[k * 16 + j];
        hmid[j] = fmaxf(s, 0.f);
    }
#pragma unroll
    for (int o = 0; o < 2; ++o) {
        float s = lb2[o];
#pragma unroll
        for (int k = 0; k < 16; ++k) s += hmid[k] * lw2[k * 2 + o];
        out[g * 2 + o] = s;
    }
}

// ---------------- launch ----------------

extern "C" void kernel_launch(void* const* d_in, const int* in_sizes, int n_in,
                              void* d_out, int out_size, void* d_ws, size_t ws_size,
                              hipStream_t stream) {
    const float* x     = (const float*)d_in[0];
    const int*   ei    = (const int*)d_in[1];
    const int*   batch = (const int*)d_in[2];
    const float* w1 = (const float*)d_in[3];  const float* b1 = (const float*)d_in[4];
    const float* w2 = (const float*)d_in[5];  const float* b2 = (const float*)d_in[6];
    const float* w3 = (const float*)d_in[7];  const float* b3 = (const float*)d_in[8];
    const float* w4 = (const float*)d_in[9];  const float* b4 = (const float*)d_in[10];
    const float* lw1 = (const float*)d_in[11]; const float* lb1 = (const float*)d_in[12];
    const float* lw2 = (const float*)d_in[13]; const float* lb2 = (const float*)d_in[14];
    float* out = (float*)d_out;

    const int n = in_sizes[0] / 512;   // 100000
    const int E = in_sizes[1] / 2;     // 320000
    const int G = 64;

    const int* src = ei;
    const int* dst = ei + E;

    char* ws = (char*)d_ws;
    size_t off = 0;
    auto alloc = [&](size_t bytes) -> void* {
        void* p = ws + off;
        off = (off + bytes + 255) & ~((size_t)255);
        return p;
    };
    float* bufA    = (float*)alloc((size_t)n * 256 * sizeof(float));
    float* bufB    = (float*)alloc((size_t)n * 256 * sizeof(float));
    int*   cnt     = (int*)alloc((size_t)n * sizeof(int));
    int*   row_ptr = (int*)alloc((size_t)(n + 1) * sizeof(int));
    int*   cursor  = (int*)alloc((size_t)n * sizeof(int));
    int*   csr     = (int*)alloc((size_t)E * sizeof(int));
    float* dinv    = (float*)alloc((size_t)n * sizeof(float));
    float* pooled  = (float*)alloc((size_t)G * 32 * sizeof(float));
    int*   bsum    = (int*)alloc(64 * sizeof(int));
    int*   boff    = (int*)alloc(64 * sizeof(int));
    (void)ws_size;

    hipMemsetAsync(cnt, 0, (size_t)n * sizeof(int), stream);
    hipMemsetAsync(cursor, 0, (size_t)n * sizeof(int), stream);

    const int nscan = (n + 4095) / 4096;   // 25 blocks

    k_count<<<(E + 255) / 256, 256, 0, stream>>>(dst, E, cnt);
    k_dinv <<<(n + 255) / 256, 256, 0, stream>>>(cnt, n, dinv);
    k_scan_sums   <<<nscan, 256, 0, stream>>>(cnt, n, bsum);
    k_scan_offsets<<<1, 64, 0, stream>>>(bsum, nscan, boff, row_ptr + n);
    k_scan_final  <<<nscan, 256, 0, stream>>>(cnt, n, boff, row_ptr);
    k_fill<<<(E + 255) / 256, 256, 0, stream>>>(src, dst, E, row_ptr, cursor, csr);

    const int gy = (n + 127) / 128;   // BM = 128 for all layers

    // layer 1: [n,512]@[512,256]  BN=128
    k_gemm_mfma<4, 4, 2, 2><<<dim3(2, gy), 256, 0, stream>>>(x, w1, bufA, n, 512, 256);
    k_agg<<<((size_t)n * 64 + 255) / 256, 256, 0, stream>>>(
        (const float4*)bufA, row_ptr, csr, dinv, b1, (float4*)bufB, n, 6, 1);

    // layer 2: [n,256]@[256,128]  BN=128
    k_gemm_mfma<4, 4, 2, 2><<<dim3(1, gy), 256, 0, stream>>>(bufB, w2, bufA, n, 256, 128);
    k_agg<<<((size_t)n * 32 + 255) / 256, 256, 0, stream>>>(
        (const float4*)bufA, row_ptr, csr, dinv, b2, (float4*)bufB, n, 5, 1);

    // layer 3: [n,128]@[128,64]  BN=64
    k_gemm_mfma<4, 2, 2, 2><<<dim3(1, gy), 256, 0, stream>>>(bufB, w3, bufA, n, 128, 64);
    k_agg<<<((size_t)n * 16 + 255) / 256, 256, 0, stream>>>(
        (const float4*)bufA, row_ptr, csr, dinv, b3, (float4*)bufB, n, 4, 1);

    // layer 4: [n,64]@[64,32]  BN=32 (no relu)
    k_gemm_mfma<2, 2, 4, 1><<<dim3(1, gy), 256, 0, stream>>>(bufB, w4, bufA, n, 64, 32);
    k_agg<<<((size_t)n * 8 + 255) / 256, 256, 0, stream>>>(
        (const float4*)bufA, row_ptr, csr, dinv, b4, (float4*)bufB, n, 3, 0);

    k_pool<<<G, 256, 0, stream>>>(bufB, batch, n, pooled);
    k_mlp<<<1, 64, 0, stream>>>(pooled, lw1, lb1, lw2, lb2, out, G);
}